// Round 3
// baseline (82.041 us; speedup 1.0000x reference)
//
#include <hip/hip_runtime.h>
#include <hip/hip_bf16.h>
#include <cstdint>

#define K_DIM 1024
#define N_DIM 128
#define BM 32
#define NT 32            // K-tiles of 32

typedef __attribute__((ext_vector_type(8))) short bf16x8;
typedef __attribute__((ext_vector_type(4))) float f32x4;
typedef unsigned short u16;
typedef unsigned int u32;

__device__ __forceinline__ float pwbq(float w) {
  w = fminf(fmaxf(w, -1.0f), 1.0f);
  return rintf(w * 127.0f) * (1.0f / 127.0f);
}

// float -> bf16 round-to-nearest-even (finite inputs only)
__device__ __forceinline__ u16 f2bf(float f) {
  union { float f; u32 u; } v; v.f = f;
  u32 r = v.u + 0x7FFFu + ((v.u >> 16) & 1u);
  return (u16)(r >> 16);
}

// Wimg[t][col][k'] : [32][128][32] bf16, fragment order. Wimg[t*4096 + c*32 + j]
// = quantize(W[(t*32+j)*128 + c]). A wave's B-frag load is 1KB contiguous.
__global__ __launch_bounds__(256) void quantW_kernel(const float* __restrict__ W,
                                                     u16* __restrict__ Wimg) {
  int H = blockIdx.x * 256 + threadIdx.x;   // 0 .. 131071
  int t = H >> 12;
  int col = (H >> 5) & 127;
  int j = H & 31;
  Wimg[H] = f2bf(pwbq(W[(t * 32 + j) * N_DIM + col]));
}

// Correctness-insurance fallback (only if d_ws is unusably small).
__global__ __launch_bounds__(256) void naive_kernel(const float* __restrict__ x,
                                                    const float* __restrict__ W,
                                                    const float* __restrict__ b,
                                                    float* __restrict__ out, int total) {
  int idx = blockIdx.x * 256 + threadIdx.x;
  if (idx >= total) return;
  int m = idx >> 7, n = idx & 127;
  float acc = pwbq(b[n]);
  for (int k = 0; k < K_DIM; ++k)
    acc = fmaf(x[(size_t)m * K_DIM + k], pwbq(W[k * N_DIM + n]), acc);
  out[idx] = acc;
}

// out[M][128] = x[M][1024] @ Wq + bq
// No LDS, no barriers: 4 independent waves per block, each owns 32 rows x 32 cols.
// A fragments read direct from x (coalesced 128B/row segments); B fragments read
// direct from L2-resident Wimg. Register pipeline 2 tiles deep (3 static slots).
__global__ __launch_bounds__(256, 4) void pwb_gemm(
    const float* __restrict__ x,
    const u16* __restrict__ Wimg,
    const float* __restrict__ bias,
    float* __restrict__ out) {

  const int tid  = threadIdx.x;
  const int lane = tid & 63;
  const int wid  = tid >> 6;     // 0..3 : 32-col quarter
  const int m0   = blockIdx.x * BM;
  const int l15  = lane & 15;
  const int lg   = lane >> 4;    // 0..3 : k-group (k = lg*8 + j)

  // per-lane base pointers
  const float* pa0 = x + (size_t)(m0 + l15) * K_DIM + lg * 8;          // q=0 rows
  const float* pa1 = pa0 + (size_t)16 * K_DIM;                         // q=1 rows
  const u16*   pb0 = Wimg + (wid * 32 + l15) * 32 + lg * 8;            // f=0 cols
  const u16*   pb1 = pb0 + 16 * 32;                                    // f=1 cols

  f32x4  af[3][2][2];   // [slot][q][half] : 8 f32 of A per quadrant
  bf16x8 bf[3][2];      // [slot][f]
  f32x4  acc[2][2] = {};

#define LOADT(S, T)                                                        \
  do {                                                                     \
    const float* a0 = pa0 + (T) * 32;                                      \
    const float* a1 = pa1 + (T) * 32;                                      \
    af[S][0][0] = *(const f32x4*)(a0);                                     \
    af[S][0][1] = *(const f32x4*)(a0 + 4);                                 \
    af[S][1][0] = *(const f32x4*)(a1);                                     \
    af[S][1][1] = *(const f32x4*)(a1 + 4);                                 \
    bf[S][0] = *(const bf16x8*)(pb0 + (T) * 4096);                         \
    bf[S][1] = *(const bf16x8*)(pb1 + (T) * 4096);                         \
  } while (0)

  LOADT(0, 0);
  LOADT(1, 1);

#pragma unroll
  for (int t = 0; t < NT; ++t) {
    const int s = t % 3;          // constant after full unroll
    if (t + 2 < NT) LOADT((t + 2) % 3, t + 2);

    bf16x8 a[2];
#pragma unroll
    for (int q = 0; q < 2; ++q) {
      union { bf16x8 v; __hip_bfloat162 p[4]; } pa;
      f32x4 f0 = af[s][q][0];
      f32x4 f1 = af[s][q][1];
      pa.p[0] = __float22bfloat162_rn(make_float2(f0[0], f0[1]));
      pa.p[1] = __float22bfloat162_rn(make_float2(f0[2], f0[3]));
      pa.p[2] = __float22bfloat162_rn(make_float2(f1[0], f1[1]));
      pa.p[3] = __float22bfloat162_rn(make_float2(f1[2], f1[3]));
      a[q] = pa.v;
    }

#pragma unroll
    for (int q = 0; q < 2; ++q)
#pragma unroll
      for (int f = 0; f < 2; ++f)
        acc[q][f] = __builtin_amdgcn_mfma_f32_16x16x32_bf16(a[q], bf[s][f], acc[q][f], 0, 0, 0);
  }
#undef LOADT

  // epilogue: C/D layout col=lane&15, row=(lane>>4)*4+j
  float bq[2];
#pragma unroll
  for (int f = 0; f < 2; ++f) bq[f] = pwbq(bias[wid * 32 + f * 16 + l15]);

#pragma unroll
  for (int q = 0; q < 2; ++q) {
    int gr0 = m0 + q * 16 + lg * 4;
#pragma unroll
    for (int f = 0; f < 2; ++f) {
      int gc = wid * 32 + f * 16 + l15;
#pragma unroll
      for (int j = 0; j < 4; ++j) {
        out[(size_t)(gr0 + j) * N_DIM + gc] = acc[q][f][j] + bq[f];
      }
    }
  }
}

extern "C" void kernel_launch(void* const* d_in, const int* in_sizes, int n_in,
                              void* d_out, int out_size, void* d_ws, size_t ws_size,
                              hipStream_t stream) {
  const float* x = (const float*)d_in[0];
  const float* W = (const float*)d_in[1];
  const float* b = (const float*)d_in[2];
  float* out = (float*)d_out;

  const int M = in_sizes[0] / K_DIM;   // 32768
  const int grid = M / BM;             // 1024

  const size_t need = (size_t)K_DIM * N_DIM * sizeof(u16);  // 256 KiB
  if (d_ws != nullptr && ws_size >= need) {
    u16* Wimg = (u16*)d_ws;
    quantW_kernel<<<(K_DIM * N_DIM) / 256, 256, 0, stream>>>(W, Wimg);
    pwb_gemm<<<grid, 256, 0, stream>>>(x, Wimg, b, out);
  } else {
    int total = M * N_DIM;
    naive_kernel<<<(total + 255) / 256, 256, 0, stream>>>(x, W, b, out, total);
  }
}

// Round 4
// 45.571 us; speedup vs baseline: 1.8003x; 1.8003x over previous
//
#include <hip/hip_runtime.h>
#include <hip/hip_bf16.h>
#include <cstdint>

#define K_DIM 1024
#define N_DIM 128
#define NT 32            // K-tiles of 32

typedef __attribute__((ext_vector_type(8))) short bf16x8;
typedef __attribute__((ext_vector_type(4))) float f32x4;
typedef unsigned short u16;
typedef unsigned int u32;

__device__ __forceinline__ float pwbq(float w) {
  w = fminf(fmaxf(w, -1.0f), 1.0f);
  return rintf(w * 127.0f) * (1.0f / 127.0f);
}

// float -> bf16 round-to-nearest-even (finite inputs only)
__device__ __forceinline__ u16 f2bf(float f) {
  union { float f; u32 u; } v; v.f = f;
  u32 r = v.u + 0x7FFFu + ((v.u >> 16) & 1u);
  return (u16)(r >> 16);
}

// Wimg[t][col][k'] : [32][128][32] bf16, fragment order. Wimg[t*4096 + c*32 + j]
// = quantize(W[(t*32+j)*128 + c]). A wave's B-frag load is 1KB contiguous.
__global__ __launch_bounds__(256) void quantW_kernel(const float* __restrict__ W,
                                                     u16* __restrict__ Wimg) {
  int H = blockIdx.x * 256 + threadIdx.x;   // 0 .. 131071
  int t = H >> 12;
  int col = (H >> 5) & 127;
  int j = H & 31;
  Wimg[H] = f2bf(pwbq(W[(t * 32 + j) * N_DIM + col]));
}

// Correctness-insurance fallback (only if d_ws is unusably small).
__global__ __launch_bounds__(256) void naive_kernel(const float* __restrict__ x,
                                                    const float* __restrict__ W,
                                                    const float* __restrict__ b,
                                                    float* __restrict__ out, int total) {
  int idx = blockIdx.x * 256 + threadIdx.x;
  if (idx >= total) return;
  int m = idx >> 7, n = idx & 127;
  float acc = pwbq(b[n]);
  for (int k = 0; k < K_DIM; ++k)
    acc = fmaf(x[(size_t)m * K_DIM + k], pwbq(W[k * N_DIM + n]), acc);
  out[idx] = acc;
}

// out[M][128] = x[M][1024] @ Wq + bq
// 4 fully independent waves per block; each wave computes 16 rows x 128 cols.
// A: per-wave PRIVATE LDS ring (3 x 2KB), staged via global_load_lds with
//    source-side XOR swizzle (linear dest; rule #21). No barriers anywhere.
// B: registers direct from L2-resident fragment-ordered Wimg (2-slot ring).
// Sync: per-wave counted vmcnt only. Full unroll -> all ring indices static.
__global__ __launch_bounds__(256, 2) void pwb_gemm(
    const float* __restrict__ x,
    const u16* __restrict__ Wimg,
    const float* __restrict__ bias,
    float* __restrict__ out) {

  __shared__ __align__(16) float As[4][3][512];   // [wave][ring][16 rows x 32 k]

  const int tid  = threadIdx.x;
  const int lane = tid & 63;
  const int wid  = tid >> 6;
  const int l15  = lane & 15;
  const int lg   = lane >> 4;                     // k-group: k = lg*8 + j
  const int rowbase = blockIdx.x * 64 + wid * 16;

  const float* xw = x + (size_t)rowbase * K_DIM;

  // Stage tile t of this wave's 16x32 A panel into ring slot s.
  // LDS dest chunk d (linear in lane, stride 16B); chunk d of row lr holds
  // logical 16B-slot (d&7)^(lr&7)  => read at phys slot = logical ^ (row&7).
  auto stageA = [&](int s, int t) {
#pragma unroll
    for (int i = 0; i < 2; ++i) {
      int d  = i * 64 + lane;         // 0..127
      int lr = d >> 3;                // local row 0..15
      int cs = (d & 7) ^ (lr & 7);    // swizzled source slot
      const float* src = xw + (size_t)lr * K_DIM + t * 32 + cs * 4;
      __builtin_amdgcn_global_load_lds(
          (const __attribute__((address_space(1))) void*)src,
          (__attribute__((address_space(3))) void*)(&As[wid][s][d * 4]), 16, 0, 0);
    }
  };

  const u16* wb = Wimg + l15 * 32 + lg * 8;       // per-lane B base
  bf16x8 bs[2][8];
  auto loadB = [&](int sb, int t) {
#pragma unroll
    for (int f = 0; f < 8; ++f)
      bs[sb][f] = *(const bf16x8*)(wb + (size_t)t * 4096 + f * 512);
  };

  f32x4 acc[8] = {};

  stageA(0, 0);
  stageA(1, 1);
  loadB(0, 0);

#pragma unroll
  for (int t = 0; t < NT; ++t) {
    if (t + 2 < NT) stageA((t + 2) % 3, t + 2);   // 2 vmem ops
    if (t + 1 < NT) loadB((t + 1) & 1, t + 1);    // 8 vmem ops

    // Retire everything up through tile t's loads; keep newer ones in flight.
    if (t + 2 < NT)      asm volatile("s_waitcnt vmcnt(10)" ::: "memory");
    else if (t + 1 < NT) asm volatile("s_waitcnt vmcnt(8)" ::: "memory");
    else                 asm volatile("s_waitcnt vmcnt(0)" ::: "memory");

    const char* ab = (const char*)&As[wid][t % 3][0];
    const int sw = l15 & 7;
    f32x4 f0 = *(const f32x4*)(ab + l15 * 128 + (((lg * 2)     ^ sw) << 4));
    f32x4 f1 = *(const f32x4*)(ab + l15 * 128 + (((lg * 2 + 1) ^ sw) << 4));
    union { bf16x8 v; __hip_bfloat162 p[4]; } pa;
    pa.p[0] = __float22bfloat162_rn(make_float2(f0[0], f0[1]));
    pa.p[1] = __float22bfloat162_rn(make_float2(f0[2], f0[3]));
    pa.p[2] = __float22bfloat162_rn(make_float2(f1[0], f1[1]));
    pa.p[3] = __float22bfloat162_rn(make_float2(f1[2], f1[3]));
    bf16x8 a = pa.v;

#pragma unroll
    for (int f = 0; f < 8; ++f)
      acc[f] = __builtin_amdgcn_mfma_f32_16x16x32_bf16(a, bs[t & 1][f], acc[f], 0, 0, 0);
  }

  // epilogue: C/D layout col=lane&15, row=(lane>>4)*4+j
#pragma unroll
  for (int f = 0; f < 8; ++f) {
    const int col = f * 16 + l15;
    const float bq = pwbq(bias[col]);
#pragma unroll
    for (int j = 0; j < 4; ++j)
      out[(size_t)(rowbase + lg * 4 + j) * N_DIM + col] = acc[f][j] + bq;
  }
}

extern "C" void kernel_launch(void* const* d_in, const int* in_sizes, int n_in,
                              void* d_out, int out_size, void* d_ws, size_t ws_size,
                              hipStream_t stream) {
  const float* x = (const float*)d_in[0];
  const float* W = (const float*)d_in[1];
  const float* b = (const float*)d_in[2];
  float* out = (float*)d_out;

  const int M = in_sizes[0] / K_DIM;   // 32768
  const int grid = M / 64;             // 512

  const size_t need = (size_t)K_DIM * N_DIM * sizeof(u16);  // 256 KiB
  if (d_ws != nullptr && ws_size >= need) {
    u16* Wimg = (u16*)d_ws;
    quantW_kernel<<<(K_DIM * N_DIM) / 256, 256, 0, stream>>>(W, Wimg);
    pwb_gemm<<<grid, 256, 0, stream>>>(x, Wimg, b, out);
  } else {
    int total = M * N_DIM;
    naive_kernel<<<(total + 255) / 256, 256, 0, stream>>>(x, W, b, out, total);
  }
}

// Round 5
// 34.900 us; speedup vs baseline: 2.3508x; 1.3058x over previous
//
#include <hip/hip_runtime.h>
#include <hip/hip_bf16.h>
#include <cstdint>

#define K_DIM 1024
#define N_DIM 128
#define BM 32
#define BK 32
#define NT (K_DIM / BK)   // 32 K-tiles

typedef __attribute__((ext_vector_type(8))) short bf16x8;
typedef __attribute__((ext_vector_type(4))) float f32x4;
typedef unsigned short u16;
typedef unsigned int u32;

__device__ __forceinline__ float pwbq(float w) {
  w = fminf(fmaxf(w, -1.0f), 1.0f);
  return rintf(w * 127.0f) * (1.0f / 127.0f);
}

// float -> bf16 round-to-nearest-even (finite inputs only)
__device__ __forceinline__ u16 f2bf(float f) {
  union { float f; u32 u; } v; v.f = f;
  u32 r = v.u + 0x7FFFu + ((v.u >> 16) & 1u);
  return (u16)(r >> 16);
}

// Build Wimg: quantized W as bf16, per K-tile in exact LDS image order with the
// read-side XOR swizzle baked in (verified in round 2).
// Half index H: t=H>>12, h=H&4095, col=h>>5, jimg=h&31,
//   j = jimg ^ ((col&3)<<3), k = t*BK+j, value = q(W[k][col]).
__global__ __launch_bounds__(256) void quantW_kernel(const float* __restrict__ W,
                                                     u16* __restrict__ Wimg) {
  int H = blockIdx.x * 256 + threadIdx.x;   // 0 .. 131071
  int t = H >> 12;
  int h = H & 4095;
  int col = h >> 5;
  int j = (h & 31) ^ ((col & 3) << 3);
  int k = t * BK + j;
  Wimg[H] = f2bf(pwbq(W[k * N_DIM + col]));
}

// Correctness-insurance fallback (only if d_ws is unusably small).
__global__ __launch_bounds__(256) void naive_kernel(const float* __restrict__ x,
                                                    const float* __restrict__ W,
                                                    const float* __restrict__ b,
                                                    float* __restrict__ out, int total) {
  int idx = blockIdx.x * 256 + threadIdx.x;
  if (idx >= total) return;
  int m = idx >> 7, n = idx & 127;
  float acc = pwbq(b[n]);
  for (int k = 0; k < K_DIM; ++k)
    acc = fmaf(x[(size_t)m * K_DIM + k], pwbq(W[k * N_DIM + n]), acc);
  out[idx] = acc;
}

// out[M][128] = x[M][1024] @ Wq + bq
// 256 threads / 4 waves; each wave: 16 rows x 64 cols. BM=32 -> grid 1024 ->
// 4 blocks/CU (36KB LDS each), 16 waves/CU. Ring-3 LDS, depth-2 prefetch,
// counted vmcnt; order per tile: vmcnt(3) -> s_barrier -> stage(t+2) -> compute
// (slot overwritten by stage(t+2) was drained by all waves at this barrier).
__global__ __launch_bounds__(256, 4) void pwb_gemm(
    const float* __restrict__ x,
    const u16* __restrict__ Wimg,   // bf16, LDS-image order, swizzle baked in
    const float* __restrict__ bias,
    float* __restrict__ out) {

  __shared__ __align__(16) float As[3][BM * BK];     // 3 x 4 KB
  __shared__ __align__(16) u16   Bs[3][N_DIM * BK];  // 3 x 8 KB

  const int tid  = threadIdx.x;
  const int lane = tid & 63;
  const int wid  = tid >> 6;
  const int wm   = wid >> 1;   // 0..1 : 16-row half
  const int wn   = wid & 1;    // 0..1 : 64-col half
  const int m0   = blockIdx.x * BM;
  const int l15  = lane & 15;
  const int lg   = lane >> 4;  // 0..3 : k-group (k = lg*8 + j)

  auto stage = [&](int s, int t) {
    // A tile: 256 16B chunks (1/thread); image chunk cd of row holds logical
    // slot (cd&7)^(row&7) (inverse of the (row&7)<<4 read swizzle).
    {
      int cd  = tid;
      int row = cd >> 3;
      int cs  = (cd & 7) ^ (row & 7);
      const float* srcA = x + (size_t)(m0 + row) * K_DIM + t * BK + cs * 4;
      __builtin_amdgcn_global_load_lds(
          (const __attribute__((address_space(1))) void*)srcA,
          (__attribute__((address_space(3))) void*)(&As[s][cd * 4]), 16, 0, 0);
    }
    // B tile: Wimg already in LDS order -> pure linear coalesced copy (2/thread).
#pragma unroll
    for (int i = 0; i < 2; ++i) {
      int cd = i * 256 + tid;
      const u16* srcB = Wimg + (size_t)t * (N_DIM * BK) + cd * 8;
      __builtin_amdgcn_global_load_lds(
          (const __attribute__((address_space(1))) void*)srcB,
          (__attribute__((address_space(3))) void*)(&Bs[s][cd * 8]), 16, 0, 0);
    }
  };

  f32x4 acc[4] = {};

  stage(0, 0);
  stage(1, 1);

#pragma unroll
  for (int t = 0; t < NT; ++t) {
    const int buf = t % 3;             // compile-time after full unroll

    if (t + 1 < NT) asm volatile("s_waitcnt vmcnt(3)" ::: "memory");
    else            asm volatile("s_waitcnt vmcnt(0)" ::: "memory");
    asm volatile("s_barrier" ::: "memory");

    if (t + 2 < NT) stage((t + 2) % 3, t + 2);

    // A fragment: k = lg*8 + j, swizzled read (row&7)<<4
    const int row  = wm * 16 + l15;
    const int base = row * 128 + lg * 32;
    const int sw   = (row & 7) << 4;
    f32x4 f0 = *(const f32x4*)((const char*)&As[buf][0] + (base ^ sw));
    f32x4 f1 = *(const f32x4*)((const char*)&As[buf][0] + ((base + 16) ^ sw));
    union { bf16x8 v; __hip_bfloat162 p[4]; } pa;
    pa.p[0] = __float22bfloat162_rn(make_float2(f0[0], f0[1]));
    pa.p[1] = __float22bfloat162_rn(make_float2(f0[2], f0[3]));
    pa.p[2] = __float22bfloat162_rn(make_float2(f1[0], f1[1]));
    pa.p[3] = __float22bfloat162_rn(make_float2(f1[2], f1[3]));
    bf16x8 a = pa.v;

    // B fragments: swizzle baked into the image: half = col*32 + (lg*8 ^ ((col&3)<<3))
#pragma unroll
    for (int f = 0; f < 4; ++f) {
      int col  = wn * 64 + f * 16 + l15;
      int hoff = col * 32 + ((lg * 8) ^ ((col & 3) << 3));
      bf16x8 bfr = *(const bf16x8*)(&Bs[buf][hoff]);
      acc[f] = __builtin_amdgcn_mfma_f32_16x16x32_bf16(a, bfr, acc[f], 0, 0, 0);
    }
  }

  // epilogue: C/D layout col=lane&15, row=(lane>>4)*4+j
#pragma unroll
  for (int f = 0; f < 4; ++f) {
    const int gc = wn * 64 + f * 16 + l15;
    const float bq = pwbq(bias[gc]);
    const int gr0 = m0 + wm * 16 + lg * 4;
#pragma unroll
    for (int j = 0; j < 4; ++j)
      out[(size_t)(gr0 + j) * N_DIM + gc] = acc[f][j] + bq;
  }
}

extern "C" void kernel_launch(void* const* d_in, const int* in_sizes, int n_in,
                              void* d_out, int out_size, void* d_ws, size_t ws_size,
                              hipStream_t stream) {
  const float* x = (const float*)d_in[0];
  const float* W = (const float*)d_in[1];
  const float* b = (const float*)d_in[2];
  float* out = (float*)d_out;

  const int M = in_sizes[0] / K_DIM;   // 32768
  const int grid = M / BM;             // 1024

  const size_t need = (size_t)K_DIM * N_DIM * sizeof(u16);  // 256 KiB
  if (d_ws != nullptr && ws_size >= need) {
    u16* Wimg = (u16*)d_ws;
    quantW_kernel<<<(K_DIM * N_DIM) / 256, 256, 0, stream>>>(W, Wimg);
    pwb_gemm<<<grid, 256, 0, stream>>>(x, Wimg, b, out);
  } else {
    int total = M * N_DIM;
    naive_kernel<<<(total + 255) / 256, 256, 0, stream>>>(x, W, b, out, total);
  }
}